// Round 10
// baseline (445.499 us; speedup 1.0000x reference)
//
#include <hip/hip_runtime.h>

#define BATCH 4
#define T 8192
#define RES 256
#define SKIPC 512
#define NCLSC 256
#define NLAYERS 30
#define T0 5120
#define TBUF 3072
#define NT 32                 // tile width — 96 tiles x 4 batch = 384 blocks
#define STR 264               // LDS row stride in shorts (528 B)
#define HFSTR 260             // fp32 LDS row stride (dwords)
#define GRIDP 384             // 2 blocks/CU (67KB LDS, <=128 VGPR) -> all co-resident
#define MAXTILES 96

typedef __attribute__((ext_vector_type(8))) short short8x;   // 8 bf16
typedef __attribute__((ext_vector_type(4))) float floatx4;   // MFMA C/D
typedef unsigned short ushort_t;
typedef unsigned long long ull;

__device__ __forceinline__ ushort_t f2bf(float f) {
    unsigned u = __float_as_uint(f);
    u += 0x7fffu + ((u >> 16) & 1u);
    return (ushort_t)(u >> 16);
}
__device__ __forceinline__ float bf2f(ushort_t h) {
    return __uint_as_float(((unsigned)h) << 16);
}

__device__ __forceinline__ ull cload(const ull* p) {
    return __hip_atomic_load(p, __ATOMIC_RELAXED, __HIP_MEMORY_SCOPE_AGENT);
}
__device__ __forceinline__ void cstore(ull* p, ull v) {
    __hip_atomic_store(p, v, __ATOMIC_RELAXED, __HIP_MEMORY_SCOPE_AGENT);
}

#define WAITF(P) while (__hip_atomic_load((P), __ATOMIC_RELAXED, __HIP_MEMORY_SCOPE_AGENT) == 0) \
                     __builtin_amdgcn_s_sleep(1)

#define MFMA __builtin_amdgcn_mfma_f32_16x16x32_bf16
#define SB() __builtin_amdgcn_sched_barrier(0)

// Coalesced weight prep for Aswz/Rswz. Each thread: ONE contiguous 64B (A) or
// 32B (R) vector read, 16B packed bf16 writes. The A read's even floats are
// tap kk=0 (output step s) and odd floats tap kk=1 (output step s+8) — zero
// overfetch, replaces the old 4B-gather prep (~50-80us -> ~10us).
__global__ __launch_bounds__(512) void prep_ar_kernel(
    const float* __restrict__ Wd, const float* __restrict__ Wr,
    ushort_t* __restrict__ Aswz, ushort_t* __restrict__ Rswz)
{
    int id = blockIdx.x * 512 + threadIdx.x;
    const int NA = 245760;                 // 30*8*8*2*64
    if (id < NA) {
        int lane = id & 63, f = (id >> 6) & 1, s = (id >> 7) & 7, wv = (id >> 10) & 7;
        int l = id >> 13;
        int row = wv * 32 + f * 16 + (lane & 15);
        int cinb = s * 32 + (lane >> 4) * 8;
        const float4* p = (const float4*)(Wd + (((size_t)l * 256 + row) * 256 + cinb) * 2);
        float4 a = p[0], b = p[1], c = p[2], d = p[3];
        ull e0 = (ull)f2bf(a.x) | ((ull)f2bf(a.z) << 16) | ((ull)f2bf(b.x) << 32) | ((ull)f2bf(b.z) << 48);
        ull e1 = (ull)f2bf(c.x) | ((ull)f2bf(c.z) << 16) | ((ull)f2bf(d.x) << 32) | ((ull)f2bf(d.z) << 48);
        ull o0 = (ull)f2bf(a.y) | ((ull)f2bf(a.w) << 16) | ((ull)f2bf(b.y) << 32) | ((ull)f2bf(b.w) << 48);
        ull o1 = (ull)f2bf(c.y) | ((ull)f2bf(c.w) << 16) | ((ull)f2bf(d.y) << 32) | ((ull)f2bf(d.w) << 48);
        ull* outE = (ull*)(Aswz + ((size_t)((((l * 8 + wv) * 16 + s) * 2 + f) * 64 + lane)) * 8);
        ull* outO = (ull*)(Aswz + ((size_t)((((l * 8 + wv) * 16 + s + 8) * 2 + f) * 64 + lane)) * 8);
        outE[0] = e0; outE[1] = e1;
        outO[0] = o0; outO[1] = o1;
        return;
    }
    id -= NA;                              // R section: 245760 threads
    {
        int lane = id & 63, f = (id >> 6) & 1, s = (id >> 7) & 7, wv = (id >> 10) & 7;
        int l = id >> 13;
        int row = wv * 32 + f * 16 + (lane & 15);
        int kb = s * 32 + (lane >> 4) * 8;
        const float4* p = (const float4*)(Wr + ((size_t)l * 256 + row) * 256 + kb);
        float4 a = p[0], b = p[1];
        ull v0 = (ull)f2bf(a.x) | ((ull)f2bf(a.y) << 16) | ((ull)f2bf(a.z) << 32) | ((ull)f2bf(a.w) << 48);
        ull v1 = (ull)f2bf(b.x) | ((ull)f2bf(b.y) << 16) | ((ull)f2bf(b.z) << 32) | ((ull)f2bf(b.w) << 48);
        ull* outp = (ull*)(Rswz + ((size_t)((((l * 8 + wv) * 8 + s) * 2 + f) * 64 + lane)) * 8);
        outp[0] = v0; outp[1] = v1;
    }
}

// WsT[l][cin][o] = Ws[l][o][cin]: 64x64 LDS-tiled transpose, padded stride 65.
__global__ __launch_bounds__(256) void prep_w_kernel(
    const float* __restrict__ Ws, ushort_t* __restrict__ WsT)
{
    __shared__ float t[64][65];
    const int bi = blockIdx.x;             // 960 = 30 l * 8 ob * 4 cb
    const int l = bi >> 5;
    const int ob = (bi & 31) >> 2, cb = bi & 3;
    const int tid = threadIdx.x;
    const int o_l = tid >> 2, part = tid & 3;
    const float* src = Ws + ((size_t)l * 512 + ob * 64 + o_l) * 256 + cb * 64 + part * 16;
    #pragma unroll
    for (int u = 0; u < 4; ++u) {
        float4 v = ((const float4*)src)[u];
        t[o_l][part * 16 + u * 4 + 0] = v.x;
        t[o_l][part * 16 + u * 4 + 1] = v.y;
        t[o_l][part * 16 + u * 4 + 2] = v.z;
        t[o_l][part * 16 + u * 4 + 3] = v.w;
    }
    __syncthreads();
    const int cin_l = tid >> 2;
    #pragma unroll
    for (int w = 0; w < 2; ++w) {
        int ow8 = (tid & 3) + w * 4;
        float x0 = t[ow8 * 8 + 0][cin_l], x1 = t[ow8 * 8 + 1][cin_l];
        float x2 = t[ow8 * 8 + 2][cin_l], x3 = t[ow8 * 8 + 3][cin_l];
        float x4 = t[ow8 * 8 + 4][cin_l], x5 = t[ow8 * 8 + 5][cin_l];
        float x6 = t[ow8 * 8 + 6][cin_l], x7 = t[ow8 * 8 + 7][cin_l];
        ull u0 = (ull)f2bf(x0) | ((ull)f2bf(x1) << 16) | ((ull)f2bf(x2) << 32) | ((ull)f2bf(x3) << 48);
        ull u1 = (ull)f2bf(x4) | ((ull)f2bf(x5) << 16) | ((ull)f2bf(x6) << 32) | ((ull)f2bf(x7) << 48);
        ull* outp = (ull*)(WsT + ((size_t)l * 256 + cb * 64 + cin_l) * 512 + ob * 64 + ow8 * 8);
        outp[0] = u0; outp[1] = u1;
    }
}

// h0[b][t][c] for t in [5120, 8191], fp32 + bf16 copies.
__global__ __launch_bounds__(256) void start_kernel(
    const float* __restrict__ x, const float* __restrict__ Wst,
    const float* __restrict__ bst, float* __restrict__ hf, ushort_t* __restrict__ hb)
{
    int id = blockIdx.x * 256 + threadIdx.x;
    int c = id & 255;
    int ti = (id >> 8) % TBUF;
    int b  = (id >> 8) / TBUF;
    int t = T0 + ti;
    float v = Wst[2 * c] * x[b * T + t - 1] + Wst[2 * c + 1] * x[b * T + t] + bst[c];
    hf[id] = v;
    hb[id] = f2bf(v);
}

// v10 = v9 (TLP, 2 blocks/CU) + sched_barrier-pinned 4-step Q/P weight windows
// (base VGPR 52 + 64 window ~ 110 < 128 cap — v7's schedule, now WITH headroom)
// + cross-layer prefetch: next layer's first conv window issues between the
// res-GEMM halves so each layer starts with weights already in registers.
__global__ __launch_bounds__(512, 2) void fused_layers_kernel(
    const float* __restrict__ hf,
    const ushort_t* __restrict__ hb0,
    const ushort_t* __restrict__ Asw,
    const float* __restrict__ bd,
    const ushort_t* __restrict__ Rsw,
    const float* __restrict__ br,
    float* __restrict__ gstore,
    ushort_t* __restrict__ hbC,
    int* __restrict__ flg)
{
    __shared__ __align__(16) ushort_t hbL[NT * STR];   // 16.9 KB: current h, bf16
    __shared__ __align__(16) ushort_t tp[NT * STR];    // 16.9 KB: halo, then gated
    __shared__ __align__(16) float hfL[NT * HFSTR];    // 33.3 KB: current h, fp32

    const int tid = threadIdx.x;
    const int wv = tid >> 6, lane = tid & 63;
    const int quad = lane >> 4, l16 = lane & 15;
    const int mb = wv * 32;
    const int u0 = l16 * STR + quad * 8;
    const int u1 = u0 + 16 * STR;
    const int B = blockIdx.x;
    const int b = B / MAXTILES, tile = B % MAXTILES;
    const int tb = 8192 - NT * (tile + 1);

    const float* __restrict__ hfg = hf + (size_t)b * TBUF * RES;
    const ushort_t* __restrict__ hbg = hb0 + (size_t)b * TBUF * RES;

    // Tile-resident state init.
    #pragma unroll
    for (int p = 0; p < 4; ++p) {
        int c = p * 512 + tid;
        int row = c >> 6, q = (c & 63) * 4;
        *(float4*)&hfL[row * HFSTR + q] =
            *(const float4*)(hfg + (size_t)(tb - T0 + row) * RES + q);
    }
    #pragma unroll
    for (int p = 0; p < 2; ++p) {
        int c = p * 512 + tid;
        int row = c >> 5, q = (c & 31) * 8;
        *(short8x*)&hbL[row * STR + q] =
            *(const short8x*)(hbg + (size_t)(tb - T0 + row) * RES + q);
    }

    #define LD(BASE, S, OFF) (*(const short8x*)((BASE) + (S) * 1024 + (OFF)))

    // Q/P weight windows (4 steps x 2 m-frags each), carried across layers.
    short8x q0a, q0b, q1a, q1b, q2a, q2b, q3a, q3b;
    short8x p0a, p0b, p1a, p1b, p2a, p2b, p3a, p3b;
    {
        const ushort_t* aw0 = Asw + (size_t)wv * 16384 + lane * 8;   // layer 0
        q0a = LD(aw0, 8, 0);  q0b = LD(aw0, 8, 512);
        q1a = LD(aw0, 9, 0);  q1b = LD(aw0, 9, 512);
        q2a = LD(aw0, 10, 0); q2b = LD(aw0, 10, 512);
        q3a = LD(aw0, 11, 0); q3b = LD(aw0, 11, 512);
    }
    __syncthreads();   // init visible before layer 0

    int rem = 3069;
    int ntiles_prev = 0;
    size_t cur_off = 0, prev_off = 0;

    for (int i = 0; i < NLAYERS; ++i) {
        const int dil = 1 << (i % 10);
        rem -= dil;
        const int s_out = 8191 - rem;
        const int ntiles = (1 + rem + 31) >> 5;
        if (tile >= ntiles) break;                     // shrinking: done forever

        const ushort_t* __restrict__ aw =
            Asw + (size_t)i * (RES * 512) + (size_t)wv * 16384 + lane * 8;
        const ushort_t* __restrict__ rw =
            Rsw + (size_t)i * (RES * RES) + (size_t)wv * 8192 + lane * 8;
        const float* __restrict__ bdL = bd + i * RES;
        const float* __restrict__ brL = br + i * RES;

        const int dil_eff = dil < NT ? dil : NT;       // halo rows [0, dil_eff)
        const int rdelta = dil < NT ? 1 : (dil >> 5);
        const int r = tile + rdelta;                   // single remote producer
        const bool remote_valid = (i > 0) && (r < ntiles_prev);
        const bool do_stage = (i == 0) || remote_valid;
        const ushort_t* hbCp = nullptr;
        if (remote_valid)
            hbCp = hbC + prev_off + ((size_t)b * ntiles_prev + r) * (size_t)dil_eff * RES;

        // tap0 B-operand base per n-frag row: own rows direct from hbL
        // (shifted), halo rows from tp.
        const ushort_t* bp0 = ((l16      >= dil_eff) ? &hbL[(l16      - dil) * STR]
                                                     : &tp[l16 * STR]) + quad * 8;
        const ushort_t* bp1 = ((16 + l16 >= dil_eff) ? &hbL[(16 + l16 - dil) * STR]
                                                     : &tp[(16 + l16) * STR]) + quad * 8;

        floatx4 acc00, acc01, acc10, acc11;
        {
            float4 c0 = *(const float4*)(bdL + mb + quad * 4);
            float4 c1 = *(const float4*)(bdL + mb + 16 + quad * 4);
            acc00 = acc01 = (floatx4){c0.x, c0.y, c0.z, c0.w};
            acc10 = acc11 = (floatx4){c1.x, c1.y, c1.z, c1.w};
        }

        #define CVH(A0_, A1_, KO) do {                                             \
            short8x g0 = *(const short8x*)&hbL[(KO) + u0];                         \
            short8x g1 = *(const short8x*)&hbL[(KO) + u1];                         \
            acc00 = MFMA(A0_, g0, acc00, 0, 0, 0);                                 \
            acc10 = MFMA(A1_, g0, acc10, 0, 0, 0);                                 \
            acc01 = MFMA(A0_, g1, acc01, 0, 0, 0);                                 \
            acc11 = MFMA(A1_, g1, acc11, 0, 0, 0);                                 \
        } while (0)
        #define CVB(A0_, A1_, KO) do {                                             \
            short8x g0 = *(const short8x*)(bp0 + (KO));                            \
            short8x g1 = *(const short8x*)(bp1 + (KO));                            \
            acc00 = MFMA(A0_, g0, acc00, 0, 0, 0);                                 \
            acc10 = MFMA(A1_, g0, acc10, 0, 0, 0);                                 \
            acc01 = MFMA(A0_, g1, acc01, 0, 0, 0);                                 \
            acc11 = MFMA(A1_, g1, acc11, 0, 0, 0);                                 \
        } while (0)

        // P <- conv tap1 high steps (aw 12..15)
        p0a = LD(aw, 12, 0); p0b = LD(aw, 12, 512);
        p1a = LD(aw, 13, 0); p1b = LD(aw, 13, 512);
        p2a = LD(aw, 14, 0); p2b = LD(aw, 14, 512);
        p3a = LD(aw, 15, 0); p3b = LD(aw, 15, 512);
        SB();
        // conv tap1 steps 0..3 with Q (prefetched last layer)
        CVH(q0a, q0b, 0); CVH(q1a, q1b, 32); CVH(q2a, q2b, 64); CVH(q3a, q3b, 96);
        SB();
        // Q <- conv tap0 steps 0..3 (fly across the poll)
        q0a = LD(aw, 0, 0); q0b = LD(aw, 0, 512);
        q1a = LD(aw, 1, 0); q1b = LD(aw, 1, 512);
        q2a = LD(aw, 2, 0); q2b = LD(aw, 2, 512);
        q3a = LD(aw, 3, 0); q3b = LD(aw, 3, 512);
        SB();
        // conv tap1 steps 4..7 with P
        CVH(p0a, p0b, 128); CVH(p1a, p1b, 160); CVH(p2a, p2b, 192); CVH(p3a, p3b, 224);
        SB();

        // ---- flag poll + halo staging into tp rows [0, dil_eff) ----
        if (do_stage) {
            if (i > 0) { WAITF(flg + ((i - 1) * BATCH + b) * MAXTILES + r); }
            if (i == 0) {
                #pragma unroll
                for (int p = 0; p < 2; ++p) {
                    int c = p * 512 + tid;
                    int row = c >> 5, q = (c & 31) * 8;
                    if (row < dil_eff) {
                        int tt = tb + row - dil;
                        tt = tt < T0 ? T0 : tt;        // clamped cols -> discarded
                        *(short8x*)&tp[row * STR + q] =
                            *(const short8x*)(hbg + (size_t)(tt - T0) * RES + q);
                    }
                }
            } else {
                #pragma unroll
                for (int p = 0; p < 2; ++p) {
                    int c = p * 512 + tid;
                    int row = c >> 5, q = (c & 31) * 8;
                    if (row < dil_eff) {
                        const ull* src = (const ull*)(hbCp + (size_t)row * RES + q);
                        ull v0 = cload(src), v1 = cload(src + 1);
                        ull* dst = (ull*)&tp[row * STR + q];
                        dst[0] = v0; dst[1] = v1;
                    }
                }
            }
            __syncthreads();                                          // S3
        }

        // P <- conv tap0 steps 4..7
        p0a = LD(aw, 4, 0); p0b = LD(aw, 4, 512);
        p1a = LD(aw, 5, 0); p1b = LD(aw, 5, 512);
        p2a = LD(aw, 6, 0); p2b = LD(aw, 6, 512);
        p3a = LD(aw, 7, 0); p3b = LD(aw, 7, 512);
        SB();
        // conv tap0 steps 0..3 with Q
        CVB(q0a, q0b, 0); CVB(q1a, q1b, 32); CVB(q2a, q2b, 64); CVB(q3a, q3b, 96);
        SB();
        // Q <- res steps 0..3
        q0a = LD(rw, 0, 0); q0b = LD(rw, 0, 512);
        q1a = LD(rw, 1, 0); q1b = LD(rw, 1, 512);
        q2a = LD(rw, 2, 0); q2b = LD(rw, 2, 512);
        q3a = LD(rw, 3, 0); q3b = LD(rw, 3, 512);
        SB();
        // conv tap0 steps 4..7 with P
        CVB(p0a, p0b, 128); CVB(p1a, p1b, 160); CVB(p2a, p2b, 192); CVB(p3a, p3b, 224);
        SB();
        // P <- res steps 4..7 (fly under the gate VALU phase)
        p0a = LD(rw, 4, 0); p0b = LD(rw, 4, 512);
        p1a = LD(rw, 5, 0); p1b = LD(rw, 5, 512);
        p2a = LD(rw, 6, 0); p2b = LD(rw, 6, 512);
        p3a = LD(rw, 7, 0); p3b = LD(rw, 7, 512);
        SB();
        #undef CVH
        #undef CVB
        __syncthreads();   // S4: conv tp/hbL reads done before gate overlays tp

        // gate -> tp[n][cin]; tanh(d)*sig(d) = (1-u)/(1+u^2), u = e^-d
        #define GATE(ACC, MF, NF) do {                                             \
            float gf[4]; ull pk = 0;                                               \
            _Pragma("unroll")                                                      \
            for (int rr = 0; rr < 4; ++rr) {                                       \
                float d = fmaxf((ACC)[rr], -30.f);                                 \
                float u = __expf(-d);                                              \
                gf[rr] = (1.f - u) * __builtin_amdgcn_rcpf(1.f + u * u);           \
                pk |= ((ull)f2bf(gf[rr])) << (16 * rr);                            \
            }                                                                      \
            const int n = (NF) * 16 + l16;                                         \
            const int m = mb + (MF) * 16 + quad * 4;                               \
            *(ull*)&tp[n * STR + m] = pk;                                          \
            if (tile == 0 && n == 31) {                                            \
                float4 g4 = {gf[0], gf[1], gf[2], gf[3]};                          \
                *(float4*)&gstore[((size_t)i * BATCH + b) * RES + m] = g4;         \
            }                                                                      \
        } while (0)
        GATE(acc00, 0, 0); GATE(acc01, 0, 1); GATE(acc10, 1, 0); GATE(acc11, 1, 1);
        #undef GATE
        __syncthreads();   // S5

        // Residual GEMM: h' = h + Wr @ gated, K=256
        floatx4 r00, r01, r10, r11;
        {
            float4 c0 = *(const float4*)(brL + mb + quad * 4);
            float4 c1 = *(const float4*)(brL + mb + 16 + quad * 4);
            r00 = r01 = (floatx4){c0.x, c0.y, c0.z, c0.w};
            r10 = r11 = (floatx4){c1.x, c1.y, c1.z, c1.w};
        }
        #define RVV(A0_, A1_, KO) do {                                             \
            short8x g0 = *(const short8x*)&tp[(KO) + u0];                          \
            short8x g1 = *(const short8x*)&tp[(KO) + u1];                          \
            r00 = MFMA(A0_, g0, r00, 0, 0, 0);                                     \
            r10 = MFMA(A1_, g0, r10, 0, 0, 0);                                     \
            r01 = MFMA(A0_, g1, r01, 0, 0, 0);                                     \
            r11 = MFMA(A1_, g1, r11, 0, 0, 0);                                     \
        } while (0)
        RVV(q0a, q0b, 0); RVV(q1a, q1b, 32); RVV(q2a, q2b, 64); RVV(q3a, q3b, 96);
        SB();
        // Q <- NEXT layer's conv tap1 steps 8..11 (hides next layer-top stall)
        if (i < NLAYERS - 1) {
            const ushort_t* awn = aw + RES * 512;
            q0a = LD(awn, 8, 0);  q0b = LD(awn, 8, 512);
            q1a = LD(awn, 9, 0);  q1b = LD(awn, 9, 512);
            q2a = LD(awn, 10, 0); q2b = LD(awn, 10, 512);
            q3a = LD(awn, 11, 0); q3b = LD(awn, 11, 512);
        }
        SB();
        RVV(p0a, p0b, 128); RVV(p1a, p1b, 160); RVV(p2a, p2b, 192); RVV(p3a, p3b, 224);
        #undef RVV

        // ---- epilogue: hfL RMW + hbL write + publish-from-registers ----
        const int dnext = (i < NLAYERS - 1) ? (1 << ((i + 1) % 10)) : 0;
        const int Ci = dnext < NT ? dnext : NT;
        const int rdn = (dnext < NT) ? 1 : (dnext >> 5);
        const bool wrC = (Ci > 0) && (tile >= rdn);
        const int pubrow = NT - Ci;
        ushort_t* hbCc = hbC + cur_off + ((size_t)b * ntiles + tile) * (size_t)Ci * RES;

        #define EPI(NF, RA, RB) do {                                               \
            const int n = (NF) * 16 + l16;                                         \
            if (tb + n >= s_out) {                                                 \
                const int m0 = mb + quad * 4;                                      \
                {                                                                  \
                    float4 ho = *(const float4*)&hfL[n * HFSTR + m0];              \
                    float4 hn = {ho.x + (RA)[0], ho.y + (RA)[1],                   \
                                 ho.z + (RA)[2], ho.w + (RA)[3]};                  \
                    *(float4*)&hfL[n * HFSTR + m0] = hn;                           \
                    ull pk = (ull)f2bf(hn.x) | ((ull)f2bf(hn.y) << 16)             \
                           | ((ull)f2bf(hn.z) << 32) | ((ull)f2bf(hn.w) << 48);    \
                    *(ull*)&hbL[n * STR + m0] = pk;                                \
                    if (wrC && n >= pubrow)                                        \
                        cstore((ull*)(hbCc + (size_t)(n - pubrow) * RES + m0), pk);\
                }                                                                  \
                {                                                                  \
                    const int m1 = m0 + 16;                                        \
                    float4 ho = *(const float4*)&hfL[n * HFSTR + m1];              \
                    float4 hn = {ho.x + (RB)[0], ho.y + (RB)[1],                   \
                                 ho.z + (RB)[2], ho.w + (RB)[3]};                  \
                    *(float4*)&hfL[n * HFSTR + m1] = hn;                           \
                    ull pk = (ull)f2bf(hn.x) | ((ull)f2bf(hn.y) << 16)             \
                           | ((ull)f2bf(hn.z) << 32) | ((ull)f2bf(hn.w) << 48);    \
                    *(ull*)&hbL[n * STR + m1] = pk;                                \
                    if (wrC && n >= pubrow)                                        \
                        cstore((ull*)(hbCc + (size_t)(n - pubrow) * RES + m1), pk);\
                }                                                                  \
            }                                                                      \
        } while (0)
        EPI(0, r00, r10);
        EPI(1, r01, r11);
        #undef EPI

        asm volatile("s_waitcnt vmcnt(0)" ::: "memory");
        __syncthreads();   // S6: epilogue LDS writes + coherent publishes drained
        if (tid == 0)
            __hip_atomic_store(flg + ((size_t)i * BATCH + b) * MAXTILES + tile, 1,
                               __ATOMIC_RELAXED, __HIP_MEMORY_SCOPE_AGENT);

        ntiles_prev = ntiles;
        prev_off = cur_off;
        cur_off += (size_t)BATCH * ntiles * Ci * RES;
    }
    #undef LD
}

// All 30 skip matvecs in parallel: block (l,b), thread o
__global__ __launch_bounds__(512) void skip_kernel(
    const ushort_t* __restrict__ WsT, const float* __restrict__ bs,
    const float* __restrict__ gstore, float* __restrict__ skip)
{
    const int l = blockIdx.x, b = blockIdx.y, o = threadIdx.x;
    const ushort_t* w = WsT + (size_t)l * 131072;
    const float* g = gstore + (size_t)(l * BATCH + b) * RES;
    float a = bs[l * SKIPC + o];
    #pragma unroll 4
    for (int cin = 0; cin < RES; ++cin)
        a = fmaf(bf2f(w[cin * SKIPC + o]), g[cin], a);
    atomicAdd(&skip[b * SKIPC + o], a);
}

// e1[b][o] = relu(W1 @ relu(skip[b]) + b1); grid (B, 16), block computes 32 outputs
__global__ __launch_bounds__(256) void end1_kernel(
    const float* __restrict__ skip, const float* __restrict__ W1,
    const float* __restrict__ b1, float* __restrict__ e1ws)
{
    __shared__ float s[SKIPC];
    __shared__ float part[256];
    const int b = blockIdx.x, og = blockIdx.y, tid = threadIdx.x;
    s[tid]       = fmaxf(skip[b * SKIPC + tid], 0.f);
    s[tid + 256] = fmaxf(skip[b * SKIPC + tid + 256], 0.f);
    __syncthreads();
    const int o_l = tid >> 3, kp = tid & 7;
    const int o = og * 32 + o_l;
    const float* w = W1 + (size_t)o * SKIPC + kp * 64;
    const float* sp = s + kp * 64;
    float a = 0.f;
    #pragma unroll 8
    for (int j = 0; j < 64; ++j) a = fmaf(w[j], sp[j], a);
    part[tid] = a;
    __syncthreads();
    if (tid < 32) {
        float r = b1[og * 32 + tid];
        #pragma unroll
        for (int k = 0; k < 8; ++k) r += part[tid * 8 + k];
        e1ws[b * SKIPC + og * 32 + tid] = fmaxf(r, 0.f);
    }
}

// out[b][cls] = W2 @ e1 + b2; grid (B, 8), block computes 32 outputs
__global__ __launch_bounds__(256) void end2_kernel(
    const float* __restrict__ e1ws, const float* __restrict__ W2,
    const float* __restrict__ b2, float* __restrict__ out)
{
    __shared__ float e[SKIPC];
    __shared__ float part[256];
    const int b = blockIdx.x, og = blockIdx.y, tid = threadIdx.x;
    e[tid]       = e1ws[b * SKIPC + tid];
    e[tid + 256] = e1ws[b * SKIPC + tid + 256];
    __syncthreads();
    const int o_l = tid >> 3, kp = tid & 7;
    const int cls = og * 32 + o_l;
    const float* w = W2 + (size_t)cls * SKIPC + kp * 64;
    const float* ep = e + kp * 64;
    float a = 0.f;
    #pragma unroll 8
    for (int j = 0; j < 64; ++j) a = fmaf(w[j], ep[j], a);
    part[tid] = a;
    __syncthreads();
    if (tid < 32) {
        float r = b2[og * 32 + tid];
        #pragma unroll
        for (int k = 0; k < 8; ++k) r += part[tid * 8 + k];
        out[b * NCLSC + og * 32 + tid] = r;
    }
}

extern "C" void kernel_launch(void* const* d_in, const int* in_sizes, int n_in,
                              void* d_out, int out_size, void* d_ws, size_t ws_size,
                              hipStream_t stream)
{
    const float* x   = (const float*)d_in[0];
    const float* Wst = (const float*)d_in[1];
    const float* bst = (const float*)d_in[2];
    const float* Wd  = (const float*)d_in[3];
    const float* bd  = (const float*)d_in[4];
    const float* Wr  = (const float*)d_in[5];
    const float* br  = (const float*)d_in[6];
    const float* Ws  = (const float*)d_in[7];
    const float* bs  = (const float*)d_in[8];
    const float* W1  = (const float*)d_in[9];
    const float* b1  = (const float*)d_in[10];
    const float* W2  = (const float*)d_in[11];
    const float* b2  = (const float*)d_in[12];
    float* out = (float*)d_out;

    // hbC size: per layer, BATCH * ntiles * Ci cols of 256 bf16 (Ci = min(dil_next,32))
    size_t hbC_shorts = 0;
    {
        int rem = 3069;
        for (int i = 0; i < NLAYERS; ++i) {
            int d = 1 << (i % 10);
            rem -= d;
            int ntl = (1 + rem + 31) >> 5;
            int dn = (i < NLAYERS - 1) ? (1 << ((i + 1) % 10)) : 0;
            int Ci = (dn < NT) ? dn : NT;
            hbC_shorts += (size_t)BATCH * ntl * Ci * RES;
        }
    }

    char* w = (char*)d_ws;
    float* hf     = (float*)w;     w += (size_t)BATCH * TBUF * RES * 4;
    ushort_t* hb0 = (ushort_t*)w;  w += (size_t)BATCH * TBUF * RES * 2;
    ushort_t* Asw = (ushort_t*)w;  w += (size_t)NLAYERS * RES * 512 * 2;
    ushort_t* Rsw = (ushort_t*)w;  w += (size_t)NLAYERS * RES * RES * 2;
    ushort_t* WsT = (ushort_t*)w;  w += (size_t)NLAYERS * RES * SKIPC * 2;
    float* gstore = (float*)w;     w += (size_t)NLAYERS * BATCH * RES * 4;
    float* skip   = (float*)w;     w += (size_t)BATCH * SKIPC * 4;
    float* e1ws   = (float*)w;     w += (size_t)BATCH * SKIPC * 4;
    ushort_t* hbC = (ushort_t*)w;  w += hbC_shorts * 2;
    int* flg      = (int*)w;       w += (size_t)NLAYERS * BATCH * MAXTILES * 4;

    prep_ar_kernel<<<960, 512, 0, stream>>>(Wd, Wr, Asw, Rsw);
    prep_w_kernel<<<960, 256, 0, stream>>>(Ws, WsT);
    start_kernel<<<(BATCH * TBUF * RES) / 256, 256, 0, stream>>>(x, Wst, bst, hf, hb0);
    hipMemsetAsync(skip, 0, BATCH * SKIPC * 4, stream);
    hipMemsetAsync(flg, 0, (size_t)NLAYERS * BATCH * MAXTILES * 4, stream);

    fused_layers_kernel<<<GRIDP, 512, 0, stream>>>(
        hf, hb0, Asw, bd, Rsw, br, gstore, hbC, flg);

    skip_kernel<<<dim3(NLAYERS, BATCH), 512, 0, stream>>>(WsT, bs, gstore, skip);
    end1_kernel<<<dim3(BATCH, 16), 256, 0, stream>>>(skip, W1, b1, e1ws);
    end2_kernel<<<dim3(BATCH, 8), 256, 0, stream>>>(e1ws, W2, b2, out);
}

// Round 11
// 409.679 us; speedup vs baseline: 1.0874x; 1.0874x over previous
//
#include <hip/hip_runtime.h>

#define BATCH 4
#define T 8192
#define RES 256
#define SKIPC 512
#define NCLSC 256
#define NLAYERS 30
#define T0 5120
#define TBUF 3072
#define NT 32                 // tile width — 96 tiles x 4 batch = 384 blocks
#define STR 264               // LDS row stride in shorts (528 B)
#define HFSTR 260             // fp32 LDS row stride (dwords)
#define GRIDP 384             // 2 blocks/CU (67KB LDS, <=128 VGPR) -> all co-resident
#define MAXTILES 96

typedef __attribute__((ext_vector_type(8))) short short8x;   // 8 bf16
typedef __attribute__((ext_vector_type(4))) float floatx4;   // MFMA C/D
typedef unsigned short ushort_t;
typedef unsigned long long ull;

__device__ __forceinline__ ushort_t f2bf(float f) {
    unsigned u = __float_as_uint(f);
    u += 0x7fffu + ((u >> 16) & 1u);
    return (ushort_t)(u >> 16);
}
__device__ __forceinline__ float bf2f(ushort_t h) {
    return __uint_as_float(((unsigned)h) << 16);
}

__device__ __forceinline__ ull cload(const ull* p) {
    return __hip_atomic_load(p, __ATOMIC_RELAXED, __HIP_MEMORY_SCOPE_AGENT);
}
__device__ __forceinline__ void cstore(ull* p, ull v) {
    __hip_atomic_store(p, v, __ATOMIC_RELAXED, __HIP_MEMORY_SCOPE_AGENT);
}

#define WAITF(P) while (__hip_atomic_load((P), __ATOMIC_RELAXED, __HIP_MEMORY_SCOPE_AGENT) == 0) \
                     __builtin_amdgcn_s_sleep(1)

#define MFMA __builtin_amdgcn_mfma_f32_16x16x32_bf16

// Coalesced weight prep for Aswz/Rswz (verified round 10). Each thread: ONE
// contiguous 64B (A) or 32B (R) vector read, 16B packed bf16 writes.
__global__ __launch_bounds__(512) void prep_ar_kernel(
    const float* __restrict__ Wd, const float* __restrict__ Wr,
    ushort_t* __restrict__ Aswz, ushort_t* __restrict__ Rswz)
{
    int id = blockIdx.x * 512 + threadIdx.x;
    const int NA = 245760;                 // 30*8*8*2*64
    if (id < NA) {
        int lane = id & 63, f = (id >> 6) & 1, s = (id >> 7) & 7, wv = (id >> 10) & 7;
        int l = id >> 13;
        int row = wv * 32 + f * 16 + (lane & 15);
        int cinb = s * 32 + (lane >> 4) * 8;
        const float4* p = (const float4*)(Wd + (((size_t)l * 256 + row) * 256 + cinb) * 2);
        float4 a = p[0], b = p[1], c = p[2], d = p[3];
        ull e0 = (ull)f2bf(a.x) | ((ull)f2bf(a.z) << 16) | ((ull)f2bf(b.x) << 32) | ((ull)f2bf(b.z) << 48);
        ull e1 = (ull)f2bf(c.x) | ((ull)f2bf(c.z) << 16) | ((ull)f2bf(d.x) << 32) | ((ull)f2bf(d.z) << 48);
        ull o0 = (ull)f2bf(a.y) | ((ull)f2bf(a.w) << 16) | ((ull)f2bf(b.y) << 32) | ((ull)f2bf(b.w) << 48);
        ull o1 = (ull)f2bf(c.y) | ((ull)f2bf(c.w) << 16) | ((ull)f2bf(d.y) << 32) | ((ull)f2bf(d.w) << 48);
        ull* outE = (ull*)(Aswz + ((size_t)((((l * 8 + wv) * 16 + s) * 2 + f) * 64 + lane)) * 8);
        ull* outO = (ull*)(Aswz + ((size_t)((((l * 8 + wv) * 16 + s + 8) * 2 + f) * 64 + lane)) * 8);
        outE[0] = e0; outE[1] = e1;
        outO[0] = o0; outO[1] = o1;
        return;
    }
    id -= NA;                              // R section: 245760 threads
    {
        int lane = id & 63, f = (id >> 6) & 1, s = (id >> 7) & 7, wv = (id >> 10) & 7;
        int l = id >> 13;
        int row = wv * 32 + f * 16 + (lane & 15);
        int kb = s * 32 + (lane >> 4) * 8;
        const float4* p = (const float4*)(Wr + ((size_t)l * 256 + row) * 256 + kb);
        float4 a = p[0], b = p[1];
        ull v0 = (ull)f2bf(a.x) | ((ull)f2bf(a.y) << 16) | ((ull)f2bf(a.z) << 32) | ((ull)f2bf(a.w) << 48);
        ull v1 = (ull)f2bf(b.x) | ((ull)f2bf(b.y) << 16) | ((ull)f2bf(b.z) << 32) | ((ull)f2bf(b.w) << 48);
        ull* outp = (ull*)(Rswz + ((size_t)((((l * 8 + wv) * 8 + s) * 2 + f) * 64 + lane)) * 8);
        outp[0] = v0; outp[1] = v1;
    }
}

// WsT[l][cin][o] = Ws[l][o][cin]: 64x64 LDS-tiled transpose, padded stride 65.
__global__ __launch_bounds__(256) void prep_w_kernel(
    const float* __restrict__ Ws, ushort_t* __restrict__ WsT)
{
    __shared__ float t[64][65];
    const int bi = blockIdx.x;             // 960 = 30 l * 8 ob * 4 cb
    const int l = bi >> 5;
    const int ob = (bi & 31) >> 2, cb = bi & 3;
    const int tid = threadIdx.x;
    const int o_l = tid >> 2, part = tid & 3;
    const float* src = Ws + ((size_t)l * 512 + ob * 64 + o_l) * 256 + cb * 64 + part * 16;
    #pragma unroll
    for (int u = 0; u < 4; ++u) {
        float4 v = ((const float4*)src)[u];
        t[o_l][part * 16 + u * 4 + 0] = v.x;
        t[o_l][part * 16 + u * 4 + 1] = v.y;
        t[o_l][part * 16 + u * 4 + 2] = v.z;
        t[o_l][part * 16 + u * 4 + 3] = v.w;
    }
    __syncthreads();
    const int cin_l = tid >> 2;
    #pragma unroll
    for (int w = 0; w < 2; ++w) {
        int ow8 = (tid & 3) + w * 4;
        float x0 = t[ow8 * 8 + 0][cin_l], x1 = t[ow8 * 8 + 1][cin_l];
        float x2 = t[ow8 * 8 + 2][cin_l], x3 = t[ow8 * 8 + 3][cin_l];
        float x4 = t[ow8 * 8 + 4][cin_l], x5 = t[ow8 * 8 + 5][cin_l];
        float x6 = t[ow8 * 8 + 6][cin_l], x7 = t[ow8 * 8 + 7][cin_l];
        ull u0 = (ull)f2bf(x0) | ((ull)f2bf(x1) << 16) | ((ull)f2bf(x2) << 32) | ((ull)f2bf(x3) << 48);
        ull u1 = (ull)f2bf(x4) | ((ull)f2bf(x5) << 16) | ((ull)f2bf(x6) << 32) | ((ull)f2bf(x7) << 48);
        ull* outp = (ull*)(WsT + ((size_t)l * 256 + cb * 64 + cin_l) * 512 + ob * 64 + ow8 * 8);
        outp[0] = u0; outp[1] = u1;
    }
}

// h0[b][t][c] for t in [5120, 8191], fp32 + bf16 copies.
__global__ __launch_bounds__(256) void start_kernel(
    const float* __restrict__ x, const float* __restrict__ Wst,
    const float* __restrict__ bst, float* __restrict__ hf, ushort_t* __restrict__ hb)
{
    int id = blockIdx.x * 256 + threadIdx.x;
    int c = id & 255;
    int ti = (id >> 8) % TBUF;
    int b  = (id >> 8) / TBUF;
    int t = T0 + ti;
    float v = Wst[2 * c] * x[b * T + t - 1] + Wst[2 * c + 1] * x[b * T + t] + bst[c];
    hf[id] = v;
    hb[id] = f2bf(v);
}

// v11 fused = EXACT v9 (best measured: 276us, VGPR 52, 2 blocks/CU TLP).
// Round 10's pinned weight windows are reverted: 3 rounds of evidence (r4 burst
// thrash, r6 sunk, r10 pinned-thrash +90MB L2 refetch) show the compiler's
// natural 1-deep window + 4 waves/SIMD TLP is the optimum for weight latency.
__global__ __launch_bounds__(512, 2) void fused_layers_kernel(
    const float* __restrict__ hf,
    const ushort_t* __restrict__ hb0,
    const ushort_t* __restrict__ Asw,
    const float* __restrict__ bd,
    const ushort_t* __restrict__ Rsw,
    const float* __restrict__ br,
    float* __restrict__ gstore,
    ushort_t* __restrict__ hbC,
    int* __restrict__ flg)
{
    __shared__ __align__(16) ushort_t hbL[NT * STR];   // 16.9 KB: current h, bf16
    __shared__ __align__(16) ushort_t tp[NT * STR];    // 16.9 KB: halo, then gated
    __shared__ __align__(16) float hfL[NT * HFSTR];    // 33.3 KB: current h, fp32

    const int tid = threadIdx.x;
    const int wv = tid >> 6, lane = tid & 63;
    const int quad = lane >> 4, l16 = lane & 15;
    const int mb = wv * 32;
    const int u0 = l16 * STR + quad * 8;
    const int u1 = u0 + 16 * STR;
    const int B = blockIdx.x;
    const int b = B / MAXTILES, tile = B % MAXTILES;
    const int tb = 8192 - NT * (tile + 1);

    const float* __restrict__ hfg = hf + (size_t)b * TBUF * RES;
    const ushort_t* __restrict__ hbg = hb0 + (size_t)b * TBUF * RES;

    // Tile-resident state init.
    #pragma unroll
    for (int p = 0; p < 4; ++p) {
        int c = p * 512 + tid;
        int row = c >> 6, q = (c & 63) * 4;
        *(float4*)&hfL[row * HFSTR + q] =
            *(const float4*)(hfg + (size_t)(tb - T0 + row) * RES + q);
    }
    #pragma unroll
    for (int p = 0; p < 2; ++p) {
        int c = p * 512 + tid;
        int row = c >> 5, q = (c & 31) * 8;
        *(short8x*)&hbL[row * STR + q] =
            *(const short8x*)(hbg + (size_t)(tb - T0 + row) * RES + q);
    }
    __syncthreads();   // init visible before layer 0

    int rem = 3069;
    int ntiles_prev = 0;
    size_t cur_off = 0, prev_off = 0;

    for (int i = 0; i < NLAYERS; ++i) {
        const int dil = 1 << (i % 10);
        rem -= dil;
        const int s_out = 8191 - rem;
        const int ntiles = (1 + rem + 31) >> 5;
        if (tile >= ntiles) break;                     // shrinking: done forever

        const ushort_t* __restrict__ aw =
            Asw + (size_t)i * (RES * 512) + (size_t)wv * 16384 + lane * 8;
        const ushort_t* __restrict__ rw =
            Rsw + (size_t)i * (RES * RES) + (size_t)wv * 8192 + lane * 8;
        const float* __restrict__ bdL = bd + i * RES;
        const float* __restrict__ brL = br + i * RES;

        const int dil_eff = dil < NT ? dil : NT;       // halo rows [0, dil_eff)
        const int rdelta = dil < NT ? 1 : (dil >> 5);
        const int r = tile + rdelta;                   // single remote producer
        const bool remote_valid = (i > 0) && (r < ntiles_prev);
        const bool do_stage = (i == 0) || remote_valid;
        const ushort_t* hbCp = nullptr;
        if (remote_valid)
            hbCp = hbC + prev_off + ((size_t)b * ntiles_prev + r) * (size_t)dil_eff * RES;

        // tap0 B-operand base per n-frag row: own rows direct from hbL
        // (shifted), halo rows from tp.
        const ushort_t* bp0 = ((l16      >= dil_eff) ? &hbL[(l16      - dil) * STR]
                                                     : &tp[l16 * STR]) + quad * 8;
        const ushort_t* bp1 = ((16 + l16 >= dil_eff) ? &hbL[(16 + l16 - dil) * STR]
                                                     : &tp[(16 + l16) * STR]) + quad * 8;

        floatx4 acc00, acc01, acc10, acc11;
        {
            float4 c0 = *(const float4*)(bdL + mb + quad * 4);
            float4 c1 = *(const float4*)(bdL + mb + 16 + quad * 4);
            acc00 = acc01 = (floatx4){c0.x, c0.y, c0.z, c0.w};
            acc10 = acc11 = (floatx4){c1.x, c1.y, c1.z, c1.w};
        }

        #define LD(BASE, S, OFF) (*(const short8x*)((BASE) + (S) * 1024 + (OFF)))

        // ---- Conv tap1 half first (B = hbL, no remote dependency) ----
        {
            short8x a0 = LD(aw, 8, 0), a1 = LD(aw, 8, 512);
            #pragma unroll
            for (int s = 0; s < 8; ++s) {
                short8x n0 = a0, n1 = a1;
                if (s < 7) { n0 = LD(aw, 9 + s, 0); n1 = LD(aw, 9 + s, 512); }
                const int ko = s * 32;
                short8x g0 = *(const short8x*)&hbL[ko + u0];
                short8x g1 = *(const short8x*)&hbL[ko + u1];
                acc00 = MFMA(a0, g0, acc00, 0, 0, 0);
                acc10 = MFMA(a1, g0, acc10, 0, 0, 0);
                acc01 = MFMA(a0, g1, acc01, 0, 0, 0);
                acc11 = MFMA(a1, g1, acc11, 0, 0, 0);
                a0 = n0; a1 = n1;
            }
        }

        // ---- flag poll + halo staging into tp rows [0, dil_eff) ----
        if (do_stage) {
            if (i > 0) { WAITF(flg + ((i - 1) * BATCH + b) * MAXTILES + r); }
            if (i == 0) {
                #pragma unroll
                for (int p = 0; p < 2; ++p) {
                    int c = p * 512 + tid;
                    int row = c >> 5, q = (c & 31) * 8;
                    if (row < dil_eff) {
                        int tt = tb + row - dil;
                        tt = tt < T0 ? T0 : tt;        // clamped cols -> discarded
                        *(short8x*)&tp[row * STR + q] =
                            *(const short8x*)(hbg + (size_t)(tt - T0) * RES + q);
                    }
                }
            } else {
                #pragma unroll
                for (int p = 0; p < 2; ++p) {
                    int c = p * 512 + tid;
                    int row = c >> 5, q = (c & 31) * 8;
                    if (row < dil_eff) {
                        const ull* src = (const ull*)(hbCp + (size_t)row * RES + q);
                        ull v0 = cload(src), v1 = cload(src + 1);
                        ull* dst = (ull*)&tp[row * STR + q];
                        dst[0] = v0; dst[1] = v1;
                    }
                }
            }
            __syncthreads();                                          // S3
        }

        // ---- Conv tap0 half (B = bp select: hbL shifted / tp halo) ----
        {
            short8x a0 = LD(aw, 0, 0), a1 = LD(aw, 0, 512);
            #pragma unroll
            for (int s = 0; s < 8; ++s) {
                short8x n0 = a0, n1 = a1;
                if (s < 7) { n0 = LD(aw, 1 + s, 0); n1 = LD(aw, 1 + s, 512); }
                const int ko = s * 32;
                short8x g0 = *(const short8x*)(bp0 + ko);
                short8x g1 = *(const short8x*)(bp1 + ko);
                acc00 = MFMA(a0, g0, acc00, 0, 0, 0);
                acc10 = MFMA(a1, g0, acc10, 0, 0, 0);
                acc01 = MFMA(a0, g1, acc01, 0, 0, 0);
                acc11 = MFMA(a1, g1, acc11, 0, 0, 0);
                a0 = n0; a1 = n1;
            }
        }

        // Res step-0 weights issued now (fly under the gate VALU phase).
        short8x ra0 = LD(rw, 0, 0), ra1 = LD(rw, 0, 512);
        __syncthreads();   // S4: conv tp/hbL reads done before gate overlays tp

        // gate -> tp[n][cin]; tanh(d)*sig(d) = (1-u)/(1+u^2), u = e^-d
        #define GATE(ACC, MF, NF) do {                                             \
            float gf[4]; ull pk = 0;                                               \
            _Pragma("unroll")                                                      \
            for (int rr = 0; rr < 4; ++rr) {                                       \
                float d = fmaxf((ACC)[rr], -30.f);                                 \
                float u = __expf(-d);                                              \
                gf[rr] = (1.f - u) * __builtin_amdgcn_rcpf(1.f + u * u);           \
                pk |= ((ull)f2bf(gf[rr])) << (16 * rr);                            \
            }                                                                      \
            const int n = (NF) * 16 + l16;                                         \
            const int m = mb + (MF) * 16 + quad * 4;                               \
            *(ull*)&tp[n * STR + m] = pk;                                          \
            if (tile == 0 && n == 31) {                                            \
                float4 g4 = {gf[0], gf[1], gf[2], gf[3]};                          \
                *(float4*)&gstore[((size_t)i * BATCH + b) * RES + m] = g4;         \
            }                                                                      \
        } while (0)
        GATE(acc00, 0, 0); GATE(acc01, 0, 1); GATE(acc10, 1, 0); GATE(acc11, 1, 1);
        #undef GATE
        __syncthreads();   // S5

        // Residual GEMM: h' = h + Wr @ gated, K=256
        floatx4 r00, r01, r10, r11;
        {
            float4 c0 = *(const float4*)(brL + mb + quad * 4);
            float4 c1 = *(const float4*)(brL + mb + 16 + quad * 4);
            r00 = r01 = (floatx4){c0.x, c0.y, c0.z, c0.w};
            r10 = r11 = (floatx4){c1.x, c1.y, c1.z, c1.w};
        }
        {
            short8x a0 = ra0, a1 = ra1;
            #pragma unroll
            for (int s = 0; s < 8; ++s) {
                short8x n0 = a0, n1 = a1;
                if (s < 7) { n0 = LD(rw, 1 + s, 0); n1 = LD(rw, 1 + s, 512); }
                const int ko = s * 32;
                short8x g0 = *(const short8x*)&tp[ko + u0];
                short8x g1 = *(const short8x*)&tp[ko + u1];
                r00 = MFMA(a0, g0, r00, 0, 0, 0);
                r10 = MFMA(a1, g0, r10, 0, 0, 0);
                r01 = MFMA(a0, g1, r01, 0, 0, 0);
                r11 = MFMA(a1, g1, r11, 0, 0, 0);
                a0 = n0; a1 = n1;
            }
        }
        #undef LD

        // ---- epilogue: hfL RMW + hbL write + publish-from-registers ----
        const int dnext = (i < NLAYERS - 1) ? (1 << ((i + 1) % 10)) : 0;
        const int Ci = dnext < NT ? dnext : NT;
        const int rdn = (dnext < NT) ? 1 : (dnext >> 5);
        const bool wrC = (Ci > 0) && (tile >= rdn);
        const int pubrow = NT - Ci;
        ushort_t* hbCc = hbC + cur_off + ((size_t)b * ntiles + tile) * (size_t)Ci * RES;

        #define EPI(NF, RA, RB) do {                                               \
            const int n = (NF) * 16 + l16;                                         \
            if (tb + n >= s_out) {                                                 \
                const int m0 = mb + quad * 4;                                      \
                {                                                                  \
                    float4 ho = *(const float4*)&hfL[n * HFSTR + m0];              \
                    float4 hn = {ho.x + (RA)[0], ho.y + (RA)[1],                   \
                                 ho.z + (RA)[2], ho.w + (RA)[3]};                  \
                    *(float4*)&hfL[n * HFSTR + m0] = hn;                           \
                    ull pk = (ull)f2bf(hn.x) | ((ull)f2bf(hn.y) << 16)             \
                           | ((ull)f2bf(hn.z) << 32) | ((ull)f2bf(hn.w) << 48);    \
                    *(ull*)&hbL[n * STR + m0] = pk;                                \
                    if (wrC && n >= pubrow)                                        \
                        cstore((ull*)(hbCc + (size_t)(n - pubrow) * RES + m0), pk);\
                }                                                                  \
                {                                                                  \
                    const int m1 = m0 + 16;                                        \
                    float4 ho = *(const float4*)&hfL[n * HFSTR + m1];              \
                    float4 hn = {ho.x + (RB)[0], ho.y + (RB)[1],                   \
                                 ho.z + (RB)[2], ho.w + (RB)[3]};                  \
                    *(float4*)&hfL[n * HFSTR + m1] = hn;                           \
                    ull pk = (ull)f2bf(hn.x) | ((ull)f2bf(hn.y) << 16)             \
                           | ((ull)f2bf(hn.z) << 32) | ((ull)f2bf(hn.w) << 48);    \
                    *(ull*)&hbL[n * STR + m1] = pk;                                \
                    if (wrC && n >= pubrow)                                        \
                        cstore((ull*)(hbCc + (size_t)(n - pubrow) * RES + m1), pk);\
                }                                                                  \
            }                                                                      \
        } while (0)
        EPI(0, r00, r10);
        EPI(1, r01, r11);
        #undef EPI

        asm volatile("s_waitcnt vmcnt(0)" ::: "memory");
        __syncthreads();   // S6: epilogue LDS writes + coherent publishes drained
        if (tid == 0)
            __hip_atomic_store(flg + ((size_t)i * BATCH + b) * MAXTILES + tile, 1,
                               __ATOMIC_RELAXED, __HIP_MEMORY_SCOPE_AGENT);

        ntiles_prev = ntiles;
        prev_off = cur_off;
        cur_off += (size_t)BATCH * ntiles * Ci * RES;
    }
}

// All 30 skip matvecs: one block per layer, all 4 batches (WsT read once,
// g staged in LDS). Was 4x redundant WsT reads across (l,b) blocks.
__global__ __launch_bounds__(512) void skip_kernel(
    const ushort_t* __restrict__ WsT, const float* __restrict__ bs,
    const float* __restrict__ gstore, float* __restrict__ skip)
{
    __shared__ float sg[BATCH * RES];
    const int l = blockIdx.x, o = threadIdx.x;
    const float* g = gstore + (size_t)l * BATCH * RES;
    sg[o] = g[o];
    sg[o + 512] = g[o + 512];
    __syncthreads();
    const ushort_t* w = WsT + (size_t)l * 131072;
    float a0 = bs[l * SKIPC + o], a1 = a0, a2 = a0, a3 = a0;
    #pragma unroll 4
    for (int cin = 0; cin < RES; ++cin) {
        float wv = bf2f(w[cin * SKIPC + o]);
        a0 = fmaf(wv, sg[cin], a0);
        a1 = fmaf(wv, sg[RES + cin], a1);
        a2 = fmaf(wv, sg[2 * RES + cin], a2);
        a3 = fmaf(wv, sg[3 * RES + cin], a3);
    }
    atomicAdd(&skip[0 * SKIPC + o], a0);
    atomicAdd(&skip[1 * SKIPC + o], a1);
    atomicAdd(&skip[2 * SKIPC + o], a2);
    atomicAdd(&skip[3 * SKIPC + o], a3);
}

// e1[b][o] = relu(W1 @ relu(skip[b]) + b1); grid (B, 16), block computes 32 outputs
__global__ __launch_bounds__(256) void end1_kernel(
    const float* __restrict__ skip, const float* __restrict__ W1,
    const float* __restrict__ b1, float* __restrict__ e1ws)
{
    __shared__ float s[SKIPC];
    __shared__ float part[256];
    const int b = blockIdx.x, og = blockIdx.y, tid = threadIdx.x;
    s[tid]       = fmaxf(skip[b * SKIPC + tid], 0.f);
    s[tid + 256] = fmaxf(skip[b * SKIPC + tid + 256], 0.f);
    __syncthreads();
    const int o_l = tid >> 3, kp = tid & 7;
    const int o = og * 32 + o_l;
    const float* w = W1 + (size_t)o * SKIPC + kp * 64;
    const float* sp = s + kp * 64;
    float a = 0.f;
    #pragma unroll 8
    for (int j = 0; j < 64; ++j) a = fmaf(w[j], sp[j], a);
    part[tid] = a;
    __syncthreads();
    if (tid < 32) {
        float r = b1[og * 32 + tid];
        #pragma unroll
        for (int k = 0; k < 8; ++k) r += part[tid * 8 + k];
        e1ws[b * SKIPC + og * 32 + tid] = fmaxf(r, 0.f);
    }
}

// out[b][cls] = W2 @ e1 + b2; grid (B, 8), block computes 32 outputs
__global__ __launch_bounds__(256) void end2_kernel(
    const float* __restrict__ e1ws, const float* __restrict__ W2,
    const float* __restrict__ b2, float* __restrict__ out)
{
    __shared__ float e[SKIPC];
    __shared__ float part[256];
    const int b = blockIdx.x, og = blockIdx.y, tid = threadIdx.x;
    e[tid]       = e1ws[b * SKIPC + tid];
    e[tid + 256] = e1ws[b * SKIPC + tid + 256];
    __syncthreads();
    const int o_l = tid >> 3, kp = tid & 7;
    const int cls = og * 32 + o_l;
    const float* w = W2 + (size_t)cls * SKIPC + kp * 64;
    const float* ep = e + kp * 64;
    float a = 0.f;
    #pragma unroll 8
    for (int j = 0; j < 64; ++j) a = fmaf(w[j], ep[j], a);
    part[tid] = a;
    __syncthreads();
    if (tid < 32) {
        float r = b2[og * 32 + tid];
        #pragma unroll
        for (int k = 0; k < 8; ++k) r += part[tid * 8 + k];
        out[b * NCLSC + og * 32 + tid] = r;
    }
}

extern "C" void kernel_launch(void* const* d_in, const int* in_sizes, int n_in,
                              void* d_out, int out_size, void* d_ws, size_t ws_size,
                              hipStream_t stream)
{
    const float* x   = (const float*)d_in[0];
    const float* Wst = (const float*)d_in[1];
    const float* bst = (const float*)d_in[2];
    const float* Wd  = (const float*)d_in[3];
    const float* bd  = (const float*)d_in[4];
    const float* Wr  = (const float*)d_in[5];
    const float* br  = (const float*)d_in[6];
    const float* Ws  = (const float*)d_in[7];
    const float* bs  = (const float*)d_in[8];
    const float* W1  = (const float*)d_in[9];
    const float* b1  = (const float*)d_in[10];
    const float* W2  = (const float*)d_in[11];
    const float* b2  = (const float*)d_in[12];
    float* out = (float*)d_out;

    // hbC size: per layer, BATCH * ntiles * Ci cols of 256 bf16 (Ci = min(dil_next,32))
    size_t hbC_shorts = 0;
    {
        int rem = 3069;
        for (int i = 0; i < NLAYERS; ++i) {
            int d = 1 << (i % 10);
            rem -= d;
            int ntl = (1 + rem + 31) >> 5;
            int dn = (i < NLAYERS - 1) ? (1 << ((i + 1) % 10)) : 0;
            int Ci = (dn < NT) ? dn : NT;
            hbC_shorts += (size_t)BATCH * ntl * Ci * RES;
        }
    }

    char* w = (char*)d_ws;
    float* hf     = (float*)w;     w += (size_t)BATCH * TBUF * RES * 4;
    ushort_t* hb0 = (ushort_t*)w;  w += (size_t)BATCH * TBUF * RES * 2;
    ushort_t* Asw = (ushort_t*)w;  w += (size_t)NLAYERS * RES * 512 * 2;
    ushort_t* Rsw = (ushort_t*)w;  w += (size_t)NLAYERS * RES * RES * 2;
    ushort_t* WsT = (ushort_t*)w;  w += (size_t)NLAYERS * RES * SKIPC * 2;
    float* gstore = (float*)w;     w += (size_t)NLAYERS * BATCH * RES * 4;
    float* skip   = (float*)w;     w += (size_t)BATCH * SKIPC * 4;
    float* e1ws   = (float*)w;     w += (size_t)BATCH * SKIPC * 4;
    ushort_t* hbC = (ushort_t*)w;  w += hbC_shorts * 2;
    int* flg      = (int*)w;       w += (size_t)NLAYERS * BATCH * MAXTILES * 4;

    prep_ar_kernel<<<960, 512, 0, stream>>>(Wd, Wr, Asw, Rsw);
    prep_w_kernel<<<960, 256, 0, stream>>>(Ws, WsT);
    start_kernel<<<(BATCH * TBUF * RES) / 256, 256, 0, stream>>>(x, Wst, bst, hf, hb0);
    hipMemsetAsync(skip, 0, BATCH * SKIPC * 4, stream);
    hipMemsetAsync(flg, 0, (size_t)NLAYERS * BATCH * MAXTILES * 4, stream);

    fused_layers_kernel<<<GRIDP, 512, 0, stream>>>(
        hf, hb0, Asw, bd, Rsw, br, gstore, hbC, flg);

    skip_kernel<<<NLAYERS, 512, 0, stream>>>(WsT, bs, gstore, skip);
    end1_kernel<<<dim3(BATCH, 16), 256, 0, stream>>>(skip, W1, b1, e1ws);
    end2_kernel<<<dim3(BATCH, 8), 256, 0, stream>>>(e1ws, W2, b2, out);
}